// Round 13
// baseline (137.368 us; speedup 1.0000x reference)
//
#include <hip/hip_runtime.h>

#define FDIM 128
#define EMB 32

// ---------------- K1: xe = x @ W  (f32 in, f32 out) ----------------
__global__ __launch_bounds__(256) void k_gemm(const float* __restrict__ x,
                                              const float* __restrict__ Wm,
                                              float* __restrict__ xe) {
    __shared__ float sW[FDIM * EMB];
    const int t = threadIdx.x;
#pragma unroll
    for (int i = 0; i < (FDIM * EMB) / (256 * 4); ++i) {
        int idx = (t + i * 256) * 4;
        *(float4*)(sW + idx) = *(const float4*)(Wm + idx);
    }
    __syncthreads();

    const int r0 = blockIdx.x * 128 + (t >> 3) * 4;
    const int e0 = (t & 7) * 4;

    float acc[4][4];
#pragma unroll
    for (int i = 0; i < 4; ++i)
#pragma unroll
        for (int j = 0; j < 4; ++j) acc[i][j] = 0.f;

    for (int k = 0; k < FDIM; k += 4) {
        float4 w0 = *(const float4*)(sW + (k + 0) * EMB + e0);
        float4 w1 = *(const float4*)(sW + (k + 1) * EMB + e0);
        float4 w2 = *(const float4*)(sW + (k + 2) * EMB + e0);
        float4 w3 = *(const float4*)(sW + (k + 3) * EMB + e0);
#pragma unroll
        for (int rr = 0; rr < 4; ++rr) {
            float4 xq = *(const float4*)(x + (size_t)(r0 + rr) * FDIM + k);
            acc[rr][0] += xq.x * w0.x + xq.y * w1.x + xq.z * w2.x + xq.w * w3.x;
            acc[rr][1] += xq.x * w0.y + xq.y * w1.y + xq.z * w2.y + xq.w * w3.y;
            acc[rr][2] += xq.x * w0.z + xq.y * w1.z + xq.z * w2.z + xq.w * w3.z;
            acc[rr][3] += xq.x * w0.w + xq.y * w1.w + xq.z * w2.w + xq.w * w3.w;
        }
    }

#pragma unroll
    for (int rr = 0; rr < 4; ++rr) {
        const size_t r = (size_t)(r0 + rr);
        float4 o; o.x = acc[rr][0]; o.y = acc[rr][1]; o.z = acc[rr][2]; o.w = acc[rr][3];
        *(float4*)(xe + r * EMB + e0) = o;
    }
}

// ---------------- K2a: per-block partial sum/min/max over graph-0 rows ----------------
__global__ __launch_bounds__(256) void k_stats_a(const float* __restrict__ xe,
                                                 float* __restrict__ psum,
                                                 float* __restrict__ pmin,
                                                 float* __restrict__ pmax) {
    __shared__ float rs[256], rmn[256], rmx[256];
    const int t = threadIdx.x;
    const int d = t & 31, rg = t >> 5;
    const int r0 = blockIdx.x * 32;

    float s = 0.f, mn = 3.4e38f, mx = -3.4e38f;
#pragma unroll
    for (int it = 0; it < 4; ++it) {
        float v = xe[(size_t)(r0 + rg + it * 8) * EMB + d];
        s += v; mn = fminf(mn, v); mx = fmaxf(mx, v);
    }
    rs[t] = s; rmn[t] = mn; rmx[t] = mx;
    __syncthreads();
#pragma unroll
    for (int st = 128; st >= 32; st >>= 1) {
        if (t < st) {
            rs[t] += rs[t + st];
            rmn[t] = fminf(rmn[t], rmn[t + st]);
            rmx[t] = fmaxf(rmx[t], rmx[t + st]);
        }
        __syncthreads();
    }
    if (t < 32) {
        psum[blockIdx.x * 32 + t] = rs[t];
        pmin[blockIdx.x * 32 + t] = rmn[t];
        pmax[blockIdx.x * 32 + t] = rmx[t];
    }
}

// ---------------- K2b: finalize centroid + scale ----------------
__global__ __launch_bounds__(64) void k_stats_b(const float* __restrict__ psum,
                                                const float* __restrict__ pmin,
                                                const float* __restrict__ pmax,
                                                int nb, int n,
                                                float* __restrict__ stats) {
    const int t = threadIdx.x;
    const int d = t & 31;
    float s = 0.f, mn = 3.4e38f, mx = -3.4e38f;
    for (int b = 0; b < nb; ++b) {
        s += psum[b * 32 + d];
        mn = fminf(mn, pmin[b * 32 + d]);
        mx = fmaxf(mx, pmax[b * 32 + d]);
    }
    const float c = s / (float)n;
    float dev = fmaxf(mx - c, c - mn);
#pragma unroll
    for (int off = 16; off >= 1; off >>= 1)
        dev = fmaxf(dev, __shfl_xor(dev, off, 32));
    if (t < 32) stats[t] = c;
    if (t == 0) stats[EMB] = 0.9f / dev;
}

// ---------------- K3: strip kernel — pairwise D -> sigmoid + index fill ----------------
// Block = 64-row strip x full 1024 cols of one graph. A staged ONCE (swizzled,
// key ((row>>2)&7)<<2); B double-buffered per 64-col tile. Inner 64x64 compute
// identical to the round-8 kernel. REGULAR float4 stores (write stream goes
// through L2/L3 write-combining; reads are ~68 MB and mostly cache-hit).
#define KEY(r) ((((r) >> 2) & 7) << 2)
__global__ __launch_bounds__(256) void k_edges_s(const float* __restrict__ xe,
                                                 const float* __restrict__ stats,
                                                 const float* __restrict__ tptr,
                                                 const float* __restrict__ thptr,
                                                 float* __restrict__ wts,
                                                 float* __restrict__ srcp,
                                                 float* __restrict__ dstp,
                                                 int n) {
    __shared__ float shA[64 * 32];
    __shared__ float shB[2][64 * 32];
    __shared__ float sqA[64];
    __shared__ float sqB[2][64];

    const int g = blockIdx.y;
    const int i0 = blockIdx.x * 64;
    const int t = threadIdx.x;
    const float scale = stats[EMB];

    const int srow = t >> 2;            // 0..63 (4 lanes per row)
    const int sdc = (t & 3) * 8;        // dims 0,8,16,24 (8 floats each)
    const int skey = KEY(srow);
    const float4 cenL = *(const float4*)(stats + sdc);
    const float4 cenH = *(const float4*)(stats + sdc + 4);
    const float* gbaseXe = xe + (size_t)g * n * EMB;

    // ---- stage A strip (once): each thread 8 floats of one row ----
    {
        const float* p = gbaseXe + (size_t)(i0 + srow) * EMB + sdc;
        float4 vL = *(const float4*)(p);
        float4 vH = *(const float4*)(p + 4);
        vL.x = (vL.x - cenL.x) * scale; vL.y = (vL.y - cenL.y) * scale;
        vL.z = (vL.z - cenL.z) * scale; vL.w = (vL.w - cenL.w) * scale;
        vH.x = (vH.x - cenH.x) * scale; vH.y = (vH.y - cenH.y) * scale;
        vH.z = (vH.z - cenH.z) * scale; vH.w = (vH.w - cenH.w) * scale;
        *(float4*)(shA + srow * 32 + (sdc ^ skey)) = vL;
        *(float4*)(shA + srow * 32 + ((sdc + 4) ^ skey)) = vH;
        float ps = vL.x*vL.x + vL.y*vL.y + vL.z*vL.z + vL.w*vL.w
                 + vH.x*vH.x + vH.y*vH.y + vH.z*vH.z + vH.w*vH.w;
        ps += __shfl_xor(ps, 1);
        ps += __shfl_xor(ps, 2);
        if ((t & 3) == 0) sqA[srow] = ps;
    }

    // ---- stage B tile 0 ----
    {
        const float* p = gbaseXe + (size_t)srow * EMB + sdc;
        float4 vL = *(const float4*)(p);
        float4 vH = *(const float4*)(p + 4);
        vL.x = (vL.x - cenL.x) * scale; vL.y = (vL.y - cenL.y) * scale;
        vL.z = (vL.z - cenL.z) * scale; vL.w = (vL.w - cenL.w) * scale;
        vH.x = (vH.x - cenH.x) * scale; vH.y = (vH.y - cenH.y) * scale;
        vH.z = (vH.z - cenH.z) * scale; vH.w = (vH.w - cenH.w) * scale;
        *(float4*)(shB[0] + srow * 32 + (sdc ^ skey)) = vL;
        *(float4*)(shB[0] + srow * 32 + ((sdc + 4) ^ skey)) = vH;
        float ps = vL.x*vL.x + vL.y*vL.y + vL.z*vL.z + vL.w*vL.w
                 + vH.x*vH.x + vH.y*vH.y + vH.z*vH.z + vH.w*vH.w;
        ps += __shfl_xor(ps, 1);
        ps += __shfl_xor(ps, 2);
        if ((t & 3) == 0) sqB[0][srow] = ps;
    }
    __syncthreads();

    const float T = *tptr;
    const float TH = fabsf(*thptr);
    const int gn = g * n;
    const size_t gbase = (size_t)g * n * n;

    const int ti = t >> 4, tj = t & 15;
    const int akey = (ti & 7) << 2;
    const int bkey = (tj & 7) << 2;
    const int ntiles = n >> 6;          // 16

    for (int jt = 0; jt < ntiles; ++jt) {
        const int cur = jt & 1;
        const int j0 = jt * 64;

        // prefetch next B tile into registers
        float4 nL, nH;
        const int have = (jt + 1 < ntiles);
        if (have) {
            const float* p = gbaseXe + (size_t)((jt + 1) * 64 + srow) * EMB + sdc;
            nL = *(const float4*)(p);
            nH = *(const float4*)(p + 4);
        }

        // ---- compute 64x64 tile (i0 rows x j0 cols) ----
        float acc[4][4];
#pragma unroll
        for (int i = 0; i < 4; ++i)
#pragma unroll
            for (int j = 0; j < 4; ++j) acc[i][j] = 0.f;

        const float* sB = shB[cur];
#pragma unroll
        for (int d = 0; d < EMB; d += 4) {
            float4 a[4], b[4];
            const int dsa = d ^ akey;
            const int dsb = d ^ bkey;
#pragma unroll
            for (int u = 0; u < 4; ++u)
                a[u] = *(const float4*)(shA + (ti * 4 + u) * 32 + dsa);
#pragma unroll
            for (int v = 0; v < 4; ++v)
                b[v] = *(const float4*)(sB + (tj * 4 + v) * 32 + dsb);
#pragma unroll
            for (int u = 0; u < 4; ++u)
#pragma unroll
                for (int v = 0; v < 4; ++v)
                    acc[u][v] += a[u].x * b[v].x + a[u].y * b[v].y +
                                 a[u].z * b[v].z + a[u].w * b[v].w;
        }

        const float4 sq4 = *(const float4*)(&sqB[cur][tj * 4]);
        const float dbase = (float)(gn + j0 + tj * 4);
        float4 dst4; dst4.x = dbase; dst4.y = dbase + 1.f;
        dst4.z = dbase + 2.f; dst4.w = dbase + 3.f;

#pragma unroll
        for (int u = 0; u < 4; ++u) {
            const int row = i0 + ti * 4 + u;
            const float sa = sqA[ti * 4 + u];
            const size_t off = gbase + (size_t)row * n + j0 + tj * 4;

            float4 w;
            {
                float D0 = fmaxf(sa + sq4.x - 2.f * acc[u][0], 0.f);
                float D1 = fmaxf(sa + sq4.y - 2.f * acc[u][1], 0.f);
                float D2 = fmaxf(sa + sq4.z - 2.f * acc[u][2], 0.f);
                float D3 = fmaxf(sa + sq4.w - 2.f * acc[u][3], 0.f);
                w.x = __builtin_amdgcn_rcpf(1.f + __expf(-(T * (TH - D0))));
                w.y = __builtin_amdgcn_rcpf(1.f + __expf(-(T * (TH - D1))));
                w.z = __builtin_amdgcn_rcpf(1.f + __expf(-(T * (TH - D2))));
                w.w = __builtin_amdgcn_rcpf(1.f + __expf(-(T * (TH - D3))));
            }
            *(float4*)(wts + off) = w;

            const float sv = (float)(gn + row);
            float4 s4; s4.x = sv; s4.y = sv; s4.z = sv; s4.w = sv;
            *(float4*)(srcp + off) = s4;
            *(float4*)(dstp + off) = dst4;
        }

        __syncthreads();   // everyone done reading shB[1-cur] (from iter jt-1)

        if (have) {
            nL.x = (nL.x - cenL.x) * scale; nL.y = (nL.y - cenL.y) * scale;
            nL.z = (nL.z - cenL.z) * scale; nL.w = (nL.w - cenL.w) * scale;
            nH.x = (nH.x - cenH.x) * scale; nH.y = (nH.y - cenH.y) * scale;
            nH.z = (nH.z - cenH.z) * scale; nH.w = (nH.w - cenH.w) * scale;
            float* dstB = shB[1 - cur];
            *(float4*)(dstB + srow * 32 + (sdc ^ skey)) = nL;
            *(float4*)(dstB + srow * 32 + ((sdc + 4) ^ skey)) = nH;
            float ps = nL.x*nL.x + nL.y*nL.y + nL.z*nL.z + nL.w*nL.w
                     + nH.x*nH.x + nH.y*nH.y + nH.z*nH.z + nH.w*nH.w;
            ps += __shfl_xor(ps, 1);
            ps += __shfl_xor(ps, 2);
            if ((t & 3) == 0) sqB[1 - cur][srow] = ps;
        }
        __syncthreads();
    }
}

extern "C" void kernel_launch(void* const* d_in, const int* in_sizes, int n_in,
                              void* d_out, int out_size, void* d_ws, size_t ws_size,
                              hipStream_t stream) {
    const float* x     = (const float*)d_in[0];
    const float* Wm    = (const float*)d_in[1];
    const float* tptr  = (const float*)d_in[2];
    const float* thptr = (const float*)d_in[3];

    const int N = in_sizes[0] / FDIM;                       // 32768
    const long long rem = (long long)out_size - (long long)N * EMB;
    int G = (rem > 0) ? (int)((3LL * N * N) / rem) : 32;    // 32
    if (G <= 0) G = 32;
    const int n = N / G;                                    // 1024
    const int nb = n / 32;

    float* out  = (float*)d_out;
    float* xe   = out;
    const long long M = (long long)G * n * n;
    float* srcp = out + (size_t)N * EMB;
    float* dstp = srcp + (size_t)M;
    float* wts  = dstp + (size_t)M;

    float* stats = (float*)d_ws;
    float* psum  = stats + 64;
    float* pmin  = psum + (size_t)nb * 32;
    float* pmax  = pmin + (size_t)nb * 32;

    k_gemm<<<N / 128, 256, 0, stream>>>(x, Wm, xe);
    k_stats_a<<<nb, 256, 0, stream>>>(xe, psum, pmin, pmax);
    k_stats_b<<<1, 64, 0, stream>>>(psum, pmin, pmax, nb, n, stats);
    dim3 ge(n / 64, G);
    k_edges_s<<<ge, 256, 0, stream>>>(xe, stats, tptr, thptr, wts, srcp, dstp, n);
}

// Round 14
// 131.898 us; speedup vs baseline: 1.0415x; 1.0415x over previous
//
#include <hip/hip_runtime.h>

#define FDIM 128
#define EMB 32

typedef __attribute__((ext_vector_type(4))) float f32x4;

static __device__ __forceinline__ void store_nt(float* p, float4 v) {
    f32x4 w; w.x = v.x; w.y = v.y; w.z = v.z; w.w = v.w;
    __builtin_nontemporal_store(w, (f32x4*)p);
}

// ---------------- K1: xe = x @ W  (f32 in, f32 out) ----------------
__global__ __launch_bounds__(256) void k_gemm(const float* __restrict__ x,
                                              const float* __restrict__ Wm,
                                              float* __restrict__ xe) {
    __shared__ float sW[FDIM * EMB];
    const int t = threadIdx.x;
#pragma unroll
    for (int i = 0; i < (FDIM * EMB) / (256 * 4); ++i) {
        int idx = (t + i * 256) * 4;
        *(float4*)(sW + idx) = *(const float4*)(Wm + idx);
    }
    __syncthreads();

    const int r0 = blockIdx.x * 128 + (t >> 3) * 4;
    const int e0 = (t & 7) * 4;

    float acc[4][4];
#pragma unroll
    for (int i = 0; i < 4; ++i)
#pragma unroll
        for (int j = 0; j < 4; ++j) acc[i][j] = 0.f;

    for (int k = 0; k < FDIM; k += 4) {
        float4 w0 = *(const float4*)(sW + (k + 0) * EMB + e0);
        float4 w1 = *(const float4*)(sW + (k + 1) * EMB + e0);
        float4 w2 = *(const float4*)(sW + (k + 2) * EMB + e0);
        float4 w3 = *(const float4*)(sW + (k + 3) * EMB + e0);
#pragma unroll
        for (int rr = 0; rr < 4; ++rr) {
            float4 xq = *(const float4*)(x + (size_t)(r0 + rr) * FDIM + k);
            acc[rr][0] += xq.x * w0.x + xq.y * w1.x + xq.z * w2.x + xq.w * w3.x;
            acc[rr][1] += xq.x * w0.y + xq.y * w1.y + xq.z * w2.y + xq.w * w3.y;
            acc[rr][2] += xq.x * w0.z + xq.y * w1.z + xq.z * w2.z + xq.w * w3.z;
            acc[rr][3] += xq.x * w0.w + xq.y * w1.w + xq.z * w2.w + xq.w * w3.w;
        }
    }

#pragma unroll
    for (int rr = 0; rr < 4; ++rr) {
        const size_t r = (size_t)(r0 + rr);
        float4 o; o.x = acc[rr][0]; o.y = acc[rr][1]; o.z = acc[rr][2]; o.w = acc[rr][3];
        *(float4*)(xe + r * EMB + e0) = o;
    }
}

// ---------------- K2a: per-block partial sum/min/max over graph-0 rows ----------------
__global__ __launch_bounds__(256) void k_stats_a(const float* __restrict__ xe,
                                                 float* __restrict__ psum,
                                                 float* __restrict__ pmin,
                                                 float* __restrict__ pmax) {
    __shared__ float rs[256], rmn[256], rmx[256];
    const int t = threadIdx.x;
    const int d = t & 31, rg = t >> 5;
    const int r0 = blockIdx.x * 32;

    float s = 0.f, mn = 3.4e38f, mx = -3.4e38f;
#pragma unroll
    for (int it = 0; it < 4; ++it) {
        float v = xe[(size_t)(r0 + rg + it * 8) * EMB + d];
        s += v; mn = fminf(mn, v); mx = fmaxf(mx, v);
    }
    rs[t] = s; rmn[t] = mn; rmx[t] = mx;
    __syncthreads();
#pragma unroll
    for (int st = 128; st >= 32; st >>= 1) {
        if (t < st) {
            rs[t] += rs[t + st];
            rmn[t] = fminf(rmn[t], rmn[t + st]);
            rmx[t] = fmaxf(rmx[t], rmx[t + st]);
        }
        __syncthreads();
    }
    if (t < 32) {
        psum[blockIdx.x * 32 + t] = rs[t];
        pmin[blockIdx.x * 32 + t] = rmn[t];
        pmax[blockIdx.x * 32 + t] = rmx[t];
    }
}

// ---------------- K2b: finalize centroid + scale ----------------
__global__ __launch_bounds__(64) void k_stats_b(const float* __restrict__ psum,
                                                const float* __restrict__ pmin,
                                                const float* __restrict__ pmax,
                                                int nb, int n,
                                                float* __restrict__ stats) {
    const int t = threadIdx.x;
    const int d = t & 31;
    float s = 0.f, mn = 3.4e38f, mx = -3.4e38f;
    for (int b = 0; b < nb; ++b) {
        s += psum[b * 32 + d];
        mn = fminf(mn, pmin[b * 32 + d]);
        mx = fmaxf(mx, pmax[b * 32 + d]);
    }
    const float c = s / (float)n;
    float dev = fmaxf(mx - c, c - mn);
#pragma unroll
    for (int off = 16; off >= 1; off >>= 1)
        dev = fmaxf(dev, __shfl_xor(dev, off, 32));
    if (t < 32) stats[t] = c;
    if (t == 0) stats[EMB] = 0.9f / dev;
}

// ---------------- K3: wide-tile fused kernel, 1KB-contiguous nt stores ----------------
// 64 rows x 256 cols per block, 256 threads. Thread (w=t>>6, l=t&63) owns
// rows i0+w*16+u (u=0..15), cols j0+l*4 -> EVERY store instruction is
// 64 lanes x 16 B = 1 KB contiguous (fill-kernel pattern) for all 3 streams.
// A-reads: whole wave reads one row -> broadcast (conflict-free).
// B-reads: 64 distinct rows l*4+v, XOR key (l&7)<<2 spreads across 8 quads.
#define KEY(r) ((((r) >> 2) & 7) << 2)
__global__ __launch_bounds__(256) void k_edges_w(const float* __restrict__ xe,
                                                 const float* __restrict__ stats,
                                                 const float* __restrict__ tptr,
                                                 const float* __restrict__ thptr,
                                                 float* __restrict__ wts,
                                                 float* __restrict__ srcp,
                                                 float* __restrict__ dstp,
                                                 int n) {
    __shared__ float shA[64 * 32];     // 8 KB
    __shared__ float shB[256 * 32];    // 32 KB
    __shared__ float sqA[64];
    __shared__ __attribute__((aligned(16))) float sqB[256];

    const int g = blockIdx.z;
    const int i0 = blockIdx.y * 64;
    const int j0 = blockIdx.x * 256;
    const int t = threadIdx.x;
    const float scale = stats[EMB];
    const float* gx = xe + (size_t)g * n * EMB;

    // ---- stage 320 rows (64 A, 256 B): 2560 float4 chunks, 10 per thread ----
#pragma unroll
    for (int c = 0; c < 10; ++c) {
        int id = t + c * 256;
        int isB = (id >= 512);
        int lid = isB ? (id - 512) : id;
        int row = lid >> 3;
        int dc = (lid & 7) * 4;
        int grow = (isB ? j0 : i0) + row;
        float4 cen = *(const float4*)(stats + dc);
        float4 v = *(const float4*)(gx + (size_t)grow * EMB + dc);
        v.x = (v.x - cen.x) * scale; v.y = (v.y - cen.y) * scale;
        v.z = (v.z - cen.z) * scale; v.w = (v.w - cen.w) * scale;
        float* sh = isB ? shB : shA;
        *(float4*)(sh + row * 32 + (dc ^ KEY(row))) = v;
        float ps = v.x * v.x + v.y * v.y + v.z * v.z + v.w * v.w;
        ps += __shfl_xor(ps, 1);
        ps += __shfl_xor(ps, 2);
        ps += __shfl_xor(ps, 4);
        if ((t & 7) == 0) { if (isB) sqB[row] = ps; else sqA[row] = ps; }
    }
    __syncthreads();

    const int w = t >> 6;        // wave id: A-rows w*16 .. w*16+15
    const int l = t & 63;        // lane: cols j0 + l*4, B-rows l*4..l*4+3
    const int keyb = (l & 7) << 2;
    const int brow = l * 4 * 32;

    float acc[16][4];
#pragma unroll
    for (int i = 0; i < 16; ++i)
#pragma unroll
        for (int j = 0; j < 4; ++j) acc[i][j] = 0.f;

    for (int d = 0; d < EMB; d += 4) {
        const int db = d ^ keyb;
        float4 b0 = *(const float4*)(shB + brow + 0 * 32 + db);
        float4 b1 = *(const float4*)(shB + brow + 1 * 32 + db);
        float4 b2 = *(const float4*)(shB + brow + 2 * 32 + db);
        float4 b3 = *(const float4*)(shB + brow + 3 * 32 + db);
#pragma unroll
        for (int u = 0; u < 16; ++u) {
            const int ar = w * 16 + u;
            float4 a = *(const float4*)(shA + ar * 32 + (d ^ KEY(ar)));
            acc[u][0] += a.x * b0.x + a.y * b0.y + a.z * b0.z + a.w * b0.w;
            acc[u][1] += a.x * b1.x + a.y * b1.y + a.z * b1.z + a.w * b1.w;
            acc[u][2] += a.x * b2.x + a.y * b2.y + a.z * b2.z + a.w * b2.w;
            acc[u][3] += a.x * b3.x + a.y * b3.y + a.z * b3.z + a.w * b3.w;
        }
    }

    const float T = *tptr;
    const float TH = fabsf(*thptr);
    const int gn = g * n;
    const size_t gbase = (size_t)g * n * n;

    const float4 sq4 = *(const float4*)(sqB + l * 4);
    const float dbase = (float)(gn + j0 + l * 4);
    float4 dst4; dst4.x = dbase; dst4.y = dbase + 1.f; dst4.z = dbase + 2.f; dst4.w = dbase + 3.f;

#pragma unroll
    for (int u = 0; u < 16; ++u) {
        const int row = i0 + w * 16 + u;
        const float sa = sqA[w * 16 + u];
        const size_t off = gbase + (size_t)row * n + j0 + l * 4;

        float4 o;
        {
            float D0 = fmaxf(sa + sq4.x - 2.f * acc[u][0], 0.f);
            float D1 = fmaxf(sa + sq4.y - 2.f * acc[u][1], 0.f);
            float D2 = fmaxf(sa + sq4.z - 2.f * acc[u][2], 0.f);
            float D3 = fmaxf(sa + sq4.w - 2.f * acc[u][3], 0.f);
            o.x = __builtin_amdgcn_rcpf(1.f + __expf(-(T * (TH - D0))));
            o.y = __builtin_amdgcn_rcpf(1.f + __expf(-(T * (TH - D1))));
            o.z = __builtin_amdgcn_rcpf(1.f + __expf(-(T * (TH - D2))));
            o.w = __builtin_amdgcn_rcpf(1.f + __expf(-(T * (TH - D3))));
        }
        store_nt(wts + off, o);

        const float sv = (float)(gn + row);
        float4 s4; s4.x = sv; s4.y = sv; s4.z = sv; s4.w = sv;
        store_nt(srcp + off, s4);
        store_nt(dstp + off, dst4);
    }
}

extern "C" void kernel_launch(void* const* d_in, const int* in_sizes, int n_in,
                              void* d_out, int out_size, void* d_ws, size_t ws_size,
                              hipStream_t stream) {
    const float* x     = (const float*)d_in[0];
    const float* Wm    = (const float*)d_in[1];
    const float* tptr  = (const float*)d_in[2];
    const float* thptr = (const float*)d_in[3];

    const int N = in_sizes[0] / FDIM;                       // 32768
    const long long rem = (long long)out_size - (long long)N * EMB;
    int G = (rem > 0) ? (int)((3LL * N * N) / rem) : 32;    // 32
    if (G <= 0) G = 32;
    const int n = N / G;                                    // 1024
    const int nb = n / 32;

    float* out  = (float*)d_out;
    float* xe   = out;
    const long long M = (long long)G * n * n;
    float* srcp = out + (size_t)N * EMB;
    float* dstp = srcp + (size_t)M;
    float* wts  = dstp + (size_t)M;

    float* stats = (float*)d_ws;
    float* psum  = stats + 64;
    float* pmin  = psum + (size_t)nb * 32;
    float* pmax  = pmin + (size_t)nb * 32;

    k_gemm<<<N / 128, 256, 0, stream>>>(x, Wm, xe);
    k_stats_a<<<nb, 256, 0, stream>>>(xe, psum, pmin, pmax);
    k_stats_b<<<1, 64, 0, stream>>>(psum, pmin, pmax, nb, n, stats);
    dim3 ge(n / 256, n / 64, G);
    k_edges_w<<<ge, 256, 0, stream>>>(xe, stats, tptr, thptr, wts, srcp, dstp, n);
}

// Round 15
// 130.456 us; speedup vs baseline: 1.0530x; 1.0111x over previous
//
#include <hip/hip_runtime.h>

#define FDIM 128
#define EMB 32

typedef __attribute__((ext_vector_type(4))) float f32x4;

static __device__ __forceinline__ void store_nt(float* p, float4 v) {
    f32x4 w; w.x = v.x; w.y = v.y; w.z = v.z; w.w = v.w;
    __builtin_nontemporal_store(w, (f32x4*)p);
}

// ---------------- K0: edge_index fill (pure fill-pattern kernel) ----------------
// src[r][j] = r ; dst[r][j] = (r & ~(n-1)) + j.  Dense regular float4 stores,
// no reads, no LDS — mimics the 6.9 TB/s fillBuffer pattern.
__global__ __launch_bounds__(256) void k_eidx(float* __restrict__ srcp,
                                              float* __restrict__ dstp,
                                              int rsh, int qmask,
                                              long long nq_per_stream) {
    const long long stride = (long long)gridDim.x * 256;
    long long id = (long long)blockIdx.x * 256 + threadIdx.x;
    const long long total = 2 * nq_per_stream;
    for (; id < total; id += stride) {
        if (id < nq_per_stream) {
            const int r = (int)(id >> rsh);
            const float fv = (float)r;
            float4 v; v.x = fv; v.y = fv; v.z = fv; v.w = fv;
            *(float4*)(srcp + id * 4) = v;
        } else {
            const long long e = id - nq_per_stream;
            const int r = (int)(e >> rsh);
            const int j = ((int)e & qmask) * 4;
            const float base = (float)((r & ~((1 << rsh) * 4 - 1) * 0) /*placeholder*/);
            // dst value = row-base + j, row-base = (r / n) * n where n = 4<<rsh
            const int n_ = 4 << rsh;
            const float b = (float)((r / n_) * n_ + j);
            float4 v; v.x = b; v.y = b + 1.f; v.z = b + 2.f; v.w = b + 3.f;
            *(float4*)(dstp + e * 4) = v;
        }
    }
}

// ---------------- K1: xe = x @ W  (f32 in, f32 out) ----------------
__global__ __launch_bounds__(256) void k_gemm(const float* __restrict__ x,
                                              const float* __restrict__ Wm,
                                              float* __restrict__ xe) {
    __shared__ float sW[FDIM * EMB];
    const int t = threadIdx.x;
#pragma unroll
    for (int i = 0; i < (FDIM * EMB) / (256 * 4); ++i) {
        int idx = (t + i * 256) * 4;
        *(float4*)(sW + idx) = *(const float4*)(Wm + idx);
    }
    __syncthreads();

    const int r0 = blockIdx.x * 128 + (t >> 3) * 4;
    const int e0 = (t & 7) * 4;

    float acc[4][4];
#pragma unroll
    for (int i = 0; i < 4; ++i)
#pragma unroll
        for (int j = 0; j < 4; ++j) acc[i][j] = 0.f;

    for (int k = 0; k < FDIM; k += 4) {
        float4 w0 = *(const float4*)(sW + (k + 0) * EMB + e0);
        float4 w1 = *(const float4*)(sW + (k + 1) * EMB + e0);
        float4 w2 = *(const float4*)(sW + (k + 2) * EMB + e0);
        float4 w3 = *(const float4*)(sW + (k + 3) * EMB + e0);
#pragma unroll
        for (int rr = 0; rr < 4; ++rr) {
            float4 xq = *(const float4*)(x + (size_t)(r0 + rr) * FDIM + k);
            acc[rr][0] += xq.x * w0.x + xq.y * w1.x + xq.z * w2.x + xq.w * w3.x;
            acc[rr][1] += xq.x * w0.y + xq.y * w1.y + xq.z * w2.y + xq.w * w3.y;
            acc[rr][2] += xq.x * w0.z + xq.y * w1.z + xq.z * w2.z + xq.w * w3.z;
            acc[rr][3] += xq.x * w0.w + xq.y * w1.w + xq.z * w2.w + xq.w * w3.w;
        }
    }

#pragma unroll
    for (int rr = 0; rr < 4; ++rr) {
        const size_t r = (size_t)(r0 + rr);
        float4 o; o.x = acc[rr][0]; o.y = acc[rr][1]; o.z = acc[rr][2]; o.w = acc[rr][3];
        *(float4*)(xe + r * EMB + e0) = o;
    }
}

// ---------------- K2a: per-block partial sum/min/max over graph-0 rows ----------------
__global__ __launch_bounds__(256) void k_stats_a(const float* __restrict__ xe,
                                                 float* __restrict__ psum,
                                                 float* __restrict__ pmin,
                                                 float* __restrict__ pmax) {
    __shared__ float rs[256], rmn[256], rmx[256];
    const int t = threadIdx.x;
    const int d = t & 31, rg = t >> 5;
    const int r0 = blockIdx.x * 32;

    float s = 0.f, mn = 3.4e38f, mx = -3.4e38f;
#pragma unroll
    for (int it = 0; it < 4; ++it) {
        float v = xe[(size_t)(r0 + rg + it * 8) * EMB + d];
        s += v; mn = fminf(mn, v); mx = fmaxf(mx, v);
    }
    rs[t] = s; rmn[t] = mn; rmx[t] = mx;
    __syncthreads();
#pragma unroll
    for (int st = 128; st >= 32; st >>= 1) {
        if (t < st) {
            rs[t] += rs[t + st];
            rmn[t] = fminf(rmn[t], rmn[t + st]);
            rmx[t] = fmaxf(rmx[t], rmx[t + st]);
        }
        __syncthreads();
    }
    if (t < 32) {
        psum[blockIdx.x * 32 + t] = rs[t];
        pmin[blockIdx.x * 32 + t] = rmn[t];
        pmax[blockIdx.x * 32 + t] = rmx[t];
    }
}

// ---------------- K2b: finalize centroid + scale ----------------
__global__ __launch_bounds__(64) void k_stats_b(const float* __restrict__ psum,
                                                const float* __restrict__ pmin,
                                                const float* __restrict__ pmax,
                                                int nb, int n,
                                                float* __restrict__ stats) {
    const int t = threadIdx.x;
    const int d = t & 31;
    float s = 0.f, mn = 3.4e38f, mx = -3.4e38f;
    for (int b = 0; b < nb; ++b) {
        s += psum[b * 32 + d];
        mn = fminf(mn, pmin[b * 32 + d]);
        mx = fmaxf(mx, pmax[b * 32 + d]);
    }
    const float c = s / (float)n;
    float dev = fmaxf(mx - c, c - mn);
#pragma unroll
    for (int off = 16; off >= 1; off >>= 1)
        dev = fmaxf(dev, __shfl_xor(dev, off, 32));
    if (t < 32) stats[t] = c;
    if (t == 0) stats[EMB] = 0.9f / dev;
}

// ---------------- K3: pairwise D -> sigmoid (wts only), round-8 structure ----------------
#define LDST 32
__global__ __launch_bounds__(256) void k_edges(const float* __restrict__ xe,
                                               const float* __restrict__ stats,
                                               const float* __restrict__ tptr,
                                               const float* __restrict__ thptr,
                                               float* __restrict__ wts,
                                               int n) {
    __shared__ float shA[64 * LDST];
    __shared__ float shB[64 * LDST];
    __shared__ float sqA[64];
    __shared__ __attribute__((aligned(16))) float sqB[64];

    const int g = blockIdx.z;
    const int i0 = blockIdx.y * 64, j0 = blockIdx.x * 64;
    const int t = threadIdx.x;
    const float scale = stats[EMB];

    const float* baseA = xe + ((size_t)g * n + i0) * EMB;
    const float* baseB = xe + ((size_t)g * n + j0) * EMB;

#pragma unroll
    for (int c = 0; c < 2; ++c) {
        int id = t + c * 256;
        int row = id >> 3;
        int dc = (id & 7) * 4;
        int dswz = dc ^ (((row >> 2) & 7) << 2);
        float4 cen = *(const float4*)(stats + dc);
        float4 va = *(const float4*)(baseA + (size_t)row * EMB + dc);
        float4 vb = *(const float4*)(baseB + (size_t)row * EMB + dc);
        va.x = (va.x - cen.x) * scale; va.y = (va.y - cen.y) * scale;
        va.z = (va.z - cen.z) * scale; va.w = (va.w - cen.w) * scale;
        vb.x = (vb.x - cen.x) * scale; vb.y = (vb.y - cen.y) * scale;
        vb.z = (vb.z - cen.z) * scale; vb.w = (vb.w - cen.w) * scale;
        *(float4*)(shA + row * LDST + dswz) = va;
        *(float4*)(shB + row * LDST + dswz) = vb;
        float pa = va.x * va.x + va.y * va.y + va.z * va.z + va.w * va.w;
        float pb = vb.x * vb.x + vb.y * vb.y + vb.z * vb.z + vb.w * vb.w;
        pa += __shfl_xor(pa, 1); pb += __shfl_xor(pb, 1);
        pa += __shfl_xor(pa, 2); pb += __shfl_xor(pb, 2);
        pa += __shfl_xor(pa, 4); pb += __shfl_xor(pb, 4);
        if ((t & 7) == 0) { sqA[row] = pa; sqB[row] = pb; }
    }
    __syncthreads();

    const int ti = t >> 4, tj = t & 15;
    const int akey = (ti & 7) << 2;
    const int bkey = (tj & 7) << 2;
    float acc[4][4];
#pragma unroll
    for (int i = 0; i < 4; ++i)
#pragma unroll
        for (int j = 0; j < 4; ++j) acc[i][j] = 0.f;

    for (int d = 0; d < EMB; d += 4) {
        float4 a[4], b[4];
        const int dsa = d ^ akey;
        const int dsb = d ^ bkey;
#pragma unroll
        for (int u = 0; u < 4; ++u)
            a[u] = *(const float4*)(shA + (ti * 4 + u) * LDST + dsa);
#pragma unroll
        for (int v = 0; v < 4; ++v)
            b[v] = *(const float4*)(shB + (tj * 4 + v) * LDST + dsb);
#pragma unroll
        for (int u = 0; u < 4; ++u)
#pragma unroll
            for (int v = 0; v < 4; ++v)
                acc[u][v] += a[u].x * b[v].x + a[u].y * b[v].y +
                             a[u].z * b[v].z + a[u].w * b[v].w;
    }

    const float T = *tptr;
    const float TH = fabsf(*thptr);
    const size_t gbase = (size_t)g * n * n;
    const float4 sq4 = *(const float4*)(sqB + tj * 4);

#pragma unroll
    for (int u = 0; u < 4; ++u) {
        const int row = i0 + ti * 4 + u;
        const float sa = sqA[ti * 4 + u];
        const size_t off = gbase + (size_t)row * n + j0 + tj * 4;

        float4 w;
        {
            float D0 = fmaxf(sa + sq4.x - 2.f * acc[u][0], 0.f);
            float D1 = fmaxf(sa + sq4.y - 2.f * acc[u][1], 0.f);
            float D2 = fmaxf(sa + sq4.z - 2.f * acc[u][2], 0.f);
            float D3 = fmaxf(sa + sq4.w - 2.f * acc[u][3], 0.f);
            w.x = __builtin_amdgcn_rcpf(1.f + __expf(-(T * (TH - D0))));
            w.y = __builtin_amdgcn_rcpf(1.f + __expf(-(T * (TH - D1))));
            w.z = __builtin_amdgcn_rcpf(1.f + __expf(-(T * (TH - D2))));
            w.w = __builtin_amdgcn_rcpf(1.f + __expf(-(T * (TH - D3))));
        }
        store_nt(wts + off, w);
    }
}

extern "C" void kernel_launch(void* const* d_in, const int* in_sizes, int n_in,
                              void* d_out, int out_size, void* d_ws, size_t ws_size,
                              hipStream_t stream) {
    const float* x     = (const float*)d_in[0];
    const float* Wm    = (const float*)d_in[1];
    const float* tptr  = (const float*)d_in[2];
    const float* thptr = (const float*)d_in[3];

    const int N = in_sizes[0] / FDIM;                       // 32768
    const long long rem = (long long)out_size - (long long)N * EMB;
    int G = (rem > 0) ? (int)((3LL * N * N) / rem) : 32;    // 32
    if (G <= 0) G = 32;
    const int n = N / G;                                    // 1024
    const int nb = n / 32;

    float* out  = (float*)d_out;
    float* xe   = out;
    const long long M = (long long)G * n * n;
    float* srcp = out + (size_t)N * EMB;
    float* dstp = srcp + (size_t)M;
    float* wts  = dstp + (size_t)M;

    float* stats = (float*)d_ws;
    float* psum  = stats + 64;
    float* pmin  = psum + (size_t)nb * 32;
    float* pmax  = pmin + (size_t)nb * 32;

    // index fill first (no deps); then gemm so xe is L2-fresh for stats/edges
    int rsh = 0; { int q = n / 4; while ((1 << rsh) < q) ++rsh; } // log2(n/4)
    const long long nq = M / 4;
    k_eidx<<<2048, 256, 0, stream>>>(srcp, dstp, rsh, (n / 4) - 1, nq);

    k_gemm<<<N / 128, 256, 0, stream>>>(x, Wm, xe);
    k_stats_a<<<nb, 256, 0, stream>>>(xe, psum, pmin, pmax);
    k_stats_b<<<1, 64, 0, stream>>>(psum, pmin, pmax, nb, n, stats);
    dim3 ge(n / 64, n / 64, G);
    k_edges<<<ge, 256, 0, stream>>>(xe, stats, tptr, thptr, wts, n);
}

// Round 16
// 101.212 us; speedup vs baseline: 1.3572x; 1.2889x over previous
//
#include <hip/hip_runtime.h>

#define FDIM 128
#define EMB 32

typedef __attribute__((ext_vector_type(4))) float f32x4;

static __device__ __forceinline__ void store_nt(float* p, float4 v) {
    f32x4 w; w.x = v.x; w.y = v.y; w.z = v.z; w.w = v.w;
    __builtin_nontemporal_store(w, (f32x4*)p);
}

// ---------------- K1: xe = x @ W  (f32 in, f32 out) ----------------
__global__ __launch_bounds__(256) void k_gemm(const float* __restrict__ x,
                                              const float* __restrict__ Wm,
                                              float* __restrict__ xe) {
    __shared__ float sW[FDIM * EMB]; // [k][e] row-major, 16 KiB
    const int t = threadIdx.x;
#pragma unroll
    for (int i = 0; i < (FDIM * EMB) / (256 * 4); ++i) {
        int idx = (t + i * 256) * 4;
        *(float4*)(sW + idx) = *(const float4*)(Wm + idx);
    }
    __syncthreads();

    const int r0 = blockIdx.x * 128 + (t >> 3) * 4;
    const int e0 = (t & 7) * 4;

    float acc[4][4];
#pragma unroll
    for (int i = 0; i < 4; ++i)
#pragma unroll
        for (int j = 0; j < 4; ++j) acc[i][j] = 0.f;

    for (int k = 0; k < FDIM; k += 4) {
        float4 w0 = *(const float4*)(sW + (k + 0) * EMB + e0);
        float4 w1 = *(const float4*)(sW + (k + 1) * EMB + e0);
        float4 w2 = *(const float4*)(sW + (k + 2) * EMB + e0);
        float4 w3 = *(const float4*)(sW + (k + 3) * EMB + e0);
#pragma unroll
        for (int rr = 0; rr < 4; ++rr) {
            float4 xq = *(const float4*)(x + (size_t)(r0 + rr) * FDIM + k);
            acc[rr][0] += xq.x * w0.x + xq.y * w1.x + xq.z * w2.x + xq.w * w3.x;
            acc[rr][1] += xq.x * w0.y + xq.y * w1.y + xq.z * w2.y + xq.w * w3.y;
            acc[rr][2] += xq.x * w0.z + xq.y * w1.z + xq.z * w2.z + xq.w * w3.z;
            acc[rr][3] += xq.x * w0.w + xq.y * w1.w + xq.z * w2.w + xq.w * w3.w;
        }
    }

#pragma unroll
    for (int rr = 0; rr < 4; ++rr) {
        const size_t r = (size_t)(r0 + rr);
        float4 o; o.x = acc[rr][0]; o.y = acc[rr][1]; o.z = acc[rr][2]; o.w = acc[rr][3];
        *(float4*)(xe + r * EMB + e0) = o;   // keep cached: consumed by stats/edges
    }
}

// ---------------- K2a: per-block partial sum/min/max over graph-0 rows ----------------
__global__ __launch_bounds__(256) void k_stats_a(const float* __restrict__ xe,
                                                 float* __restrict__ psum,
                                                 float* __restrict__ pmin,
                                                 float* __restrict__ pmax) {
    __shared__ float rs[256], rmn[256], rmx[256];
    const int t = threadIdx.x;
    const int d = t & 31, rg = t >> 5;
    const int r0 = blockIdx.x * 32;

    float s = 0.f, mn = 3.4e38f, mx = -3.4e38f;
#pragma unroll
    for (int it = 0; it < 4; ++it) {
        float v = xe[(size_t)(r0 + rg + it * 8) * EMB + d];
        s += v; mn = fminf(mn, v); mx = fmaxf(mx, v);
    }
    rs[t] = s; rmn[t] = mn; rmx[t] = mx;
    __syncthreads();
#pragma unroll
    for (int st = 128; st >= 32; st >>= 1) {
        if (t < st) {
            rs[t] += rs[t + st];
            rmn[t] = fminf(rmn[t], rmn[t + st]);
            rmx[t] = fmaxf(rmx[t], rmx[t + st]);
        }
        __syncthreads();
    }
    if (t < 32) {
        psum[blockIdx.x * 32 + t] = rs[t];
        pmin[blockIdx.x * 32 + t] = rmn[t];
        pmax[blockIdx.x * 32 + t] = rmx[t];
    }
}

// ---------------- K2b: finalize centroid + scale ----------------
__global__ __launch_bounds__(64) void k_stats_b(const float* __restrict__ psum,
                                                const float* __restrict__ pmin,
                                                const float* __restrict__ pmax,
                                                int nb, int n,
                                                float* __restrict__ stats) {
    const int t = threadIdx.x;
    const int d = t & 31;
    float s = 0.f, mn = 3.4e38f, mx = -3.4e38f;
    for (int b = 0; b < nb; ++b) {
        s += psum[b * 32 + d];
        mn = fminf(mn, pmin[b * 32 + d]);
        mx = fmaxf(mx, pmax[b * 32 + d]);
    }
    const float c = s / (float)n;
    float dev = fmaxf(mx - c, c - mn);
#pragma unroll
    for (int off = 16; off >= 1; off >>= 1)
        dev = fmaxf(dev, __shfl_xor(dev, off, 32));
    if (t < 32) stats[t] = c;
    if (t == 0) stats[EMB] = 0.9f / dev;
}

// ---------------- K3: fused pairwise D -> sigmoid + edge_index fill ----------------
// grid (n/64, n/64, G); block 256; 64x64 tile; thread owns 4 rows x 4
// consecutive cols -> float4 nt-stores (no L2 allocate: keeps xe resident).
// LDS stride 32; BOTH tiles XOR-swizzled (d ^= ((row>>2)&7)<<2): compute reads
// conflict-free, staging writes ~4-way (cheap), sq pass folded into staging.
#define LDST 32
__global__ __launch_bounds__(256) void k_edges(const float* __restrict__ xe,
                                               const float* __restrict__ stats,
                                               const float* __restrict__ tptr,
                                               const float* __restrict__ thptr,
                                               float* __restrict__ wts,
                                               float* __restrict__ srcp,
                                               float* __restrict__ dstp,
                                               int n) {
    __shared__ float shA[64 * LDST];
    __shared__ float shB[64 * LDST];
    __shared__ float sqA[64];
    __shared__ __attribute__((aligned(16))) float sqB[64];

    const int g = blockIdx.z;
    const int i0 = blockIdx.y * 64, j0 = blockIdx.x * 64;
    const int t = threadIdx.x;
    const float scale = stats[EMB];

    const float* baseA = xe + ((size_t)g * n + i0) * EMB;
    const float* baseB = xe + ((size_t)g * n + j0) * EMB;

#pragma unroll
    for (int c = 0; c < 2; ++c) {
        int id = t + c * 256;
        int row = id >> 3;
        int dc = (id & 7) * 4;
        int dswz = dc ^ (((row >> 2) & 7) << 2);
        float4 cen = *(const float4*)(stats + dc);
        float4 va = *(const float4*)(baseA + (size_t)row * EMB + dc);
        float4 vb = *(const float4*)(baseB + (size_t)row * EMB + dc);
        va.x = (va.x - cen.x) * scale; va.y = (va.y - cen.y) * scale;
        va.z = (va.z - cen.z) * scale; va.w = (va.w - cen.w) * scale;
        vb.x = (vb.x - cen.x) * scale; vb.y = (vb.y - cen.y) * scale;
        vb.z = (vb.z - cen.z) * scale; vb.w = (vb.w - cen.w) * scale;
        *(float4*)(shA + row * LDST + dswz) = va;
        *(float4*)(shB + row * LDST + dswz) = vb;
        float pa = va.x * va.x + va.y * va.y + va.z * va.z + va.w * va.w;
        float pb = vb.x * vb.x + vb.y * vb.y + vb.z * vb.z + vb.w * vb.w;
        pa += __shfl_xor(pa, 1); pb += __shfl_xor(pb, 1);
        pa += __shfl_xor(pa, 2); pb += __shfl_xor(pb, 2);
        pa += __shfl_xor(pa, 4); pb += __shfl_xor(pb, 4);
        if ((t & 7) == 0) { sqA[row] = pa; sqB[row] = pb; }
    }
    __syncthreads();

    const int ti = t >> 4, tj = t & 15;
    const int akey = (ti & 7) << 2;
    const int bkey = (tj & 7) << 2;
    float acc[4][4];
#pragma unroll
    for (int i = 0; i < 4; ++i)
#pragma unroll
        for (int j = 0; j < 4; ++j) acc[i][j] = 0.f;

    for (int d = 0; d < EMB; d += 4) {
        float4 a[4], b[4];
        const int dsa = d ^ akey;
        const int dsb = d ^ bkey;
#pragma unroll
        for (int u = 0; u < 4; ++u)
            a[u] = *(const float4*)(shA + (ti * 4 + u) * LDST + dsa);
#pragma unroll
        for (int v = 0; v < 4; ++v)
            b[v] = *(const float4*)(shB + (tj * 4 + v) * LDST + dsb);
#pragma unroll
        for (int u = 0; u < 4; ++u)
#pragma unroll
            for (int v = 0; v < 4; ++v)
                acc[u][v] += a[u].x * b[v].x + a[u].y * b[v].y +
                             a[u].z * b[v].z + a[u].w * b[v].w;
    }

    const float T = *tptr;
    const float TH = fabsf(*thptr);
    const int gn = g * n;
    const size_t gbase = (size_t)g * n * n;

    const float4 sq4 = *(const float4*)(sqB + tj * 4);
    const float dbase = (float)(gn + j0 + tj * 4);
    float4 dst4; dst4.x = dbase; dst4.y = dbase + 1.f; dst4.z = dbase + 2.f; dst4.w = dbase + 3.f;

#pragma unroll
    for (int u = 0; u < 4; ++u) {
        const int row = i0 + ti * 4 + u;
        const float sa = sqA[ti * 4 + u];
        const size_t off = gbase + (size_t)row * n + j0 + tj * 4;

        float4 w;
        {
            float D0 = fmaxf(sa + sq4.x - 2.f * acc[u][0], 0.f);
            float D1 = fmaxf(sa + sq4.y - 2.f * acc[u][1], 0.f);
            float D2 = fmaxf(sa + sq4.z - 2.f * acc[u][2], 0.f);
            float D3 = fmaxf(sa + sq4.w - 2.f * acc[u][3], 0.f);
            w.x = __builtin_amdgcn_rcpf(1.f + __expf(-(T * (TH - D0))));
            w.y = __builtin_amdgcn_rcpf(1.f + __expf(-(T * (TH - D1))));
            w.z = __builtin_amdgcn_rcpf(1.f + __expf(-(T * (TH - D2))));
            w.w = __builtin_amdgcn_rcpf(1.f + __expf(-(T * (TH - D3))));
        }
        store_nt(wts + off, w);

        const float sv = (float)(gn + row);
        float4 s4; s4.x = sv; s4.y = sv; s4.z = sv; s4.w = sv;
        store_nt(srcp + off, s4);
        store_nt(dstp + off, dst4);
    }
}

extern "C" void kernel_launch(void* const* d_in, const int* in_sizes, int n_in,
                              void* d_out, int out_size, void* d_ws, size_t ws_size,
                              hipStream_t stream) {
    const float* x     = (const float*)d_in[0];
    const float* Wm    = (const float*)d_in[1];
    const float* tptr  = (const float*)d_in[2];
    const float* thptr = (const float*)d_in[3];

    const int N = in_sizes[0] / FDIM;                       // 32768
    const long long rem = (long long)out_size - (long long)N * EMB;
    int G = (rem > 0) ? (int)((3LL * N * N) / rem) : 32;    // 32
    if (G <= 0) G = 32;
    const int n = N / G;                                    // 1024
    const int nb = n / 32;

    float* out  = (float*)d_out;
    float* xe   = out;
    const long long M = (long long)G * n * n;
    float* srcp = out + (size_t)N * EMB;
    float* dstp = srcp + (size_t)M;
    float* wts  = dstp + (size_t)M;

    float* stats = (float*)d_ws;
    float* psum  = stats + 64;
    float* pmin  = psum + (size_t)nb * 32;
    float* pmax  = pmin + (size_t)nb * 32;

    k_gemm<<<N / 128, 256, 0, stream>>>(x, Wm, xe);
    k_stats_a<<<nb, 256, 0, stream>>>(xe, psum, pmin, pmax);
    k_stats_b<<<1, 64, 0, stream>>>(psum, pmin, pmax, nb, n, stats);
    dim3 ge(n / 64, n / 64, G);
    k_edges<<<ge, 256, 0, stream>>>(xe, stats, tptr, thptr, wts, srcp, dstp, n);
}